// Round 1
// 468.881 us; speedup vs baseline: 1.0716x; 1.0716x over previous
//
#include <hip/hip_runtime.h>
#include <cstdint>
#include <cstddef>

// TSPEdgeEmbedding on MI355X.
// Outputs (flat float32 in d_out, in reference return order):
//   [0, 2048000)              x = init_embeddings passthrough [B*n, D]
//   [2048000, 2848000)        edge_index row 0 (src), as float
//   [2848000, 3648000)        edge_index row 1 (dst), as float
//   [3648000, 106048000)      edge_emb [B*n*k, D] = dist*W + b
//
// One wave (64 lanes) per node. Lane l owns candidates j = l + 64*s,
// s in [0,16) -- strided => conflict-free LDS reads (consecutive lanes
// read consecutive float2).
//
// Selection via 64-bit packed keys: key = (f32_bits(dist) << 32) | j,
// bit-cast to double. dist >= 0 => sign bit 0 => uint64 bit order ==
// double value order; hi <= 0x7F800000 => exponent field < 0x7FF =>
// always finite, fmin/fmax exact. Min over keys == (min dist, tie ->
// min j), exactly matching lax.top_k's stable tiebreak. The winner's
// index falls out of the min's low 32 bits -- no ballot/ffs needed.
//
// Each lane bitonic-sorts its 16 keys once (registers only); a pop is a
// 1-lane masked shift of the sorted list, and the lane min is always
// key[0]. The edge_emb row for rank r is written INSIDE round r (all
// lanes know the broadcast min), overlapping stores with the reduction
// latency chain instead of serializing after it.

namespace {

constexpr int kB  = 16;
constexpr int kN  = 1000;
constexpr int kD  = 128;
constexpr int kK  = 50;
constexpr int kCPL = 16;                               // candidates per lane (64*16 = 1024 >= 1000)
constexpr int kNodesPerBlock = 4;                      // 4 waves / 256-thread block
constexpr int kBlocksPerBatch = kN / kNodesPerBlock;   // 250 (exact)

__device__ __forceinline__ double pack_key(float dd, int j) {
  const unsigned long long u =
      ((unsigned long long)__float_as_uint(dd) << 32) | (unsigned)j;
  return __longlong_as_double((long long)u);
}

__global__ __launch_bounds__(256)
void tsp_edge_kernel(const float* __restrict__ locs,
                     const float* __restrict__ init_emb,
                     const float* __restrict__ W,
                     const float* __restrict__ bias,
                     float* __restrict__ out)
{
#pragma clang fp contract(off)   // match numpy/XLA: separate mul/add rounding, no FMA
  const int tid  = threadIdx.x;
  const int wave = tid >> 6;
  const int lane = tid & 63;
  const int blk  = blockIdx.x;
  const int b    = blk / kBlocksPerBatch;
  const int node_in_b = (blk % kBlocksPerBatch) * kNodesPerBlock + wave;
  const int node = b * kN + node_in_b;    // global node id (= src index)

  // ---- stage this batch's locs into LDS (shared by the 4 waves) ----
  __shared__ float2 sloc[kN];
  {
    const float4* gl4 = reinterpret_cast<const float4*>(locs + (size_t)b * kN * 2);
    float4* sl4 = reinterpret_cast<float4*>(sloc);
    for (int t = tid; t < kN / 2; t += 256) sl4[t] = gl4[t];
  }
  __syncthreads();

  const float2 my = sloc[node_in_b];

  // ---- per-lane candidate keys (registers), strided ownership ----
  double key[kCPL];
#pragma unroll
  for (int s = 0; s < kCPL; ++s) {
    const int j = lane + (s << 6);
    const bool valid = (j < kN) && (j != node_in_b);
    const float2 pj = sloc[(j < kN) ? j : 0];     // conflict-free: lanes consecutive
    const float dx = my.x - pj.x;
    const float dy = my.y - pj.y;
    const float d2 = dx * dx + dy * dy;           // contract(off): matches np bitwise
    float dd = sqrtf(d2 + 1e-12f);
    if (!valid) dd = INFINITY;                    // hi = 0x7F800000, still a finite double key
    key[s] = pack_key(dd, j);
  }

  // ---- one-time per-lane bitonic sort (ascending), 80 CE, all in VGPRs ----
#pragma unroll
  for (int kk = 2; kk <= kCPL; kk <<= 1) {
#pragma unroll
    for (int jj = kk >> 1; jj > 0; jj >>= 1) {
#pragma unroll
      for (int i = 0; i < kCPL; ++i) {
        const int l2 = i ^ jj;
        if (l2 > i) {
          const double a  = key[i];
          const double c  = key[l2];
          const double lo = fmin(a, c);
          const double hi = fmax(a, c);
          if ((i & kk) == 0) { key[i] = lo; key[l2] = hi; }
          else               { key[i] = hi; key[l2] = lo; }
        }
      }
    }
  }

  // ---- output geometry ----
  constexpr size_t X_SZ    = (size_t)kB * kN * kD;   // 2,048,000
  constexpr size_t E_SZ    = (size_t)kB * kN * kK;   // 800,000
  constexpr size_t SRC_OFF = X_SZ;
  constexpr size_t DST_OFF = X_SZ + E_SZ;
  constexpr size_t EMB_OFF = X_SZ + 2 * E_SZ;

  // per-lane Linear(1,D) coefficients: lane covers cols [2*lane, 2*lane+2)
  const float2 wv = reinterpret_cast<const float2*>(W)[lane];
  const float2 bv = reinterpret_cast<const float2*>(bias)[lane];
  float* ebase = out + EMB_OFF + (size_t)node * (kK * kD);
  const int col2 = lane * 2;

  int res_j = 0;   // lane r (< kK) ends holding rank-r neighbor index
  const double INFK = __builtin_inf();  // > every key; never equals one

  // ---- 50 extraction rounds, emb-row store fused into each round ----
#pragma unroll 1
  for (int r = 0; r < kK; ++r) {
    double m = key[0];
#pragma unroll
    for (int off = 32; off >= 1; off >>= 1)
      m = fmin(m, __shfl_xor(m, off, 64));

    const unsigned long long u = (unsigned long long)__double_as_longlong(m);
    const float dist = __uint_as_float((unsigned)(u >> 32));
    if (lane == r) res_j = (int)(u & 0xFFFFFFFFull);

    // all 64 lanes write their float2 of edge_emb row r (512 B coalesced)
    float2 v;
    v.x = dist * wv.x + bv.x;
    v.y = dist * wv.y + bv.y;
    *reinterpret_cast<float2*>(ebase + (size_t)r * kD + col2) = v;

    // owner (unique: keys are distinct) pops its sorted list head
    if (key[0] == m) {
#pragma unroll
      for (int s = 0; s < kCPL - 1; ++s) key[s] = key[s + 1];
      key[kCPL - 1] = INFK;
    }
  }

  // ---- x passthrough: one row (128 floats) per wave, float2 per lane ----
  {
    const float2* srcp = reinterpret_cast<const float2*>(init_emb + (size_t)node * kD);
    float2* dstp = reinterpret_cast<float2*>(out + (size_t)node * kD);
    dstp[lane] = srcp[lane];
  }

  // ---- edge_index (float values; max 15999 exact in f32) ----
  if (lane < kK) {
    out[SRC_OFF + (size_t)node * kK + lane] = (float)node;
    out[DST_OFF + (size_t)node * kK + lane] = (float)(b * kN + res_j);
  }
}

} // namespace

extern "C" void kernel_launch(void* const* d_in, const int* in_sizes, int n_in,
                              void* d_out, int out_size, void* d_ws, size_t ws_size,
                              hipStream_t stream) {
  const float* locs = (const float*)d_in[0];   // [16,1000,2]
  const float* emb  = (const float*)d_in[1];   // [16,1000,128]
  const float* W    = (const float*)d_in[2];   // [1,128]
  const float* bias = (const float*)d_in[3];   // [128]
  float* out = (float*)d_out;

  dim3 grid(kB * kBlocksPerBatch);   // 4000 blocks = 16000 waves = 1 per node
  dim3 block(256);
  hipLaunchKernelGGL(tsp_edge_kernel, grid, block, 0, stream, locs, emb, W, bias, out);
}